// Round 1
// baseline (373.082 us; speedup 1.0000x reference)
//
#include <hip/hip_runtime.h>
#include <hip/hip_bf16.h>
#include <stdint.h>

#define NUM_TOKENS 8192
#define HIDDEN 1024
#define NEXP 8
#define TOPK 2

typedef __bf16 bf16;
typedef __bf16 bf16x4 __attribute__((ext_vector_type(4)));
typedef __bf16 bf16x8 __attribute__((ext_vector_type(8)));
typedef float f32x4 __attribute__((ext_vector_type(4)));

// global -> LDS direct copy, 16B per lane. LDS dest must be lane-contiguous
// (wave-uniform base + lane*16). Casts go through integers: AS1 is value-
// identical to generic; AS3 is the low 32 bits of a generic LDS pointer
// (CK's amd_direct_load.hpp pattern).
__device__ __forceinline__ void gld_lds16(const void* g, void* l) {
  __builtin_amdgcn_global_load_lds(
      (const __attribute__((address_space(1))) void*)(uintptr_t)g,
      (__attribute__((address_space(3))) void*)(uint32_t)(uintptr_t)l,
      16, 0, 0);
}

// ---------------------------------------------------------------------------
// Kernel 1: gating (fp32 exact) + routing scatter + x fp32->bf16 conversion.
// One wave per token.
// ---------------------------------------------------------------------------
__global__ __launch_bounds__(256) void gate_route_kernel(
    const float* __restrict__ x, const float* __restrict__ gw,
    bf16* __restrict__ xbf, int* __restrict__ cnt, int* __restrict__ tok,
    float* __restrict__ wt)
{
  const int wid  = threadIdx.x >> 6;
  const int lane = threadIdx.x & 63;
  const int t = blockIdx.x * 4 + wid;   // grid = 2048 -> t in [0, 8192)

  const float* xrow = x + (size_t)t * HIDDEN;
  bf16* xbrow = xbf + (size_t)t * HIDDEN;

  float acc[NEXP];
#pragma unroll
  for (int e = 0; e < NEXP; ++e) acc[e] = 0.f;

#pragma unroll
  for (int it = 0; it < 4; ++it) {
    const int idx = it * 256 + lane * 4;
    float4 xv = *(const float4*)(xrow + idx);
    bf16x4 xb;
    xb[0] = (bf16)xv.x; xb[1] = (bf16)xv.y; xb[2] = (bf16)xv.z; xb[3] = (bf16)xv.w;
    *(bf16x4*)(xbrow + idx) = xb;
#pragma unroll
    for (int e = 0; e < NEXP; ++e) {
      float4 gv = *(const float4*)(gw + e * HIDDEN + idx);
      acc[e] += xv.x * gv.x + xv.y * gv.y + xv.z * gv.z + xv.w * gv.w;
    }
  }
  // butterfly reduce each logit across the 64-lane wave
#pragma unroll
  for (int e = 0; e < NEXP; ++e) {
#pragma unroll
    for (int off = 32; off > 0; off >>= 1)
      acc[e] += __shfl_xor(acc[e], off, 64);
  }

  if (lane == 0) {
    float m = acc[0];
#pragma unroll
    for (int e = 1; e < NEXP; ++e) m = fmaxf(m, acc[e]);
    float p[NEXP]; float s = 0.f;
#pragma unroll
    for (int e = 0; e < NEXP; ++e) { p[e] = expf(acc[e] - m); s += p[e]; }
    const float inv = 1.f / s;
#pragma unroll
    for (int e = 0; e < NEXP; ++e) p[e] *= inv;
    // top-2, ties -> lower index (jax.lax.top_k semantics)
    int i0 = 0; float p0 = p[0];
#pragma unroll
    for (int e = 1; e < NEXP; ++e) if (p[e] > p0) { p0 = p[e]; i0 = e; }
    int i1 = -1; float p1 = -1.f;
#pragma unroll
    for (int e = 0; e < NEXP; ++e) if (e != i0 && p[e] > p1) { p1 = p[e]; i1 = e; }

    int pos0 = atomicAdd(&cnt[0 * NEXP + i0], 1);
    tok[(0 * NEXP + i0) * NUM_TOKENS + pos0] = t;
    wt [(0 * NEXP + i0) * NUM_TOKENS + pos0] = p0;
    int pos1 = atomicAdd(&cnt[1 * NEXP + i1], 1);
    tok[(1 * NEXP + i1) * NUM_TOKENS + pos1] = t;
    wt [(1 * NEXP + i1) * NUM_TOKENS + pos1] = p1;
  }
}

// ---------------------------------------------------------------------------
// Kernel 2: expert weights fp32 -> bf16
// ---------------------------------------------------------------------------
__global__ __launch_bounds__(256) void convert_w_kernel(
    const float* __restrict__ w, bf16* __restrict__ wbf)
{
  const size_t i = ((size_t)blockIdx.x * 256 + threadIdx.x) * 4;
  float4 v = *(const float4*)(w + i);
  bf16x4 b;
  b[0] = (bf16)v.x; b[1] = (bf16)v.y; b[2] = (bf16)v.z; b[3] = (bf16)v.w;
  *(bf16x4*)(wbf + i) = b;
}

// ---------------------------------------------------------------------------
// Kernel 3: grouped GEMM over one top-k slot. C[row,h] = sum_d X[tok[row],d]*W[e,h,d]
// 128x128 tile, BK=32, 4 waves of 4x4 mfma_f32_16x16x32_bf16 (m97 structure).
// PASS 0: out = w*y ; PASS 1: out += w*y  (separate launches -> no races)
// ---------------------------------------------------------------------------
template <int PASS>
__global__ __launch_bounds__(256) void moe_gemm_kernel(
    const bf16* __restrict__ xbf, const bf16* __restrict__ wbf,
    const int* __restrict__ cnt, const int* __restrict__ tok,
    const float* __restrict__ wt, float* __restrict__ out)
{
  const int e  = blockIdx.z;
  const int mt = blockIdx.y;
  const int nt = blockIdx.x;
  const int list = PASS * NEXP + e;
  const int count = cnt[list];
  const int m0 = mt * 128;
  if (m0 >= count) return;
  const int rows = min(128, count - m0);

  __shared__ __align__(16) bf16 As[128 * 32];
  __shared__ __align__(16) bf16 Bs[128 * 32];
  __shared__ int   tok_s[128];
  __shared__ float wt_s[128];

  const int tid = threadIdx.x;
  if (tid < 128) {
    if (tid < rows) {
      tok_s[tid] = tok[(size_t)list * NUM_TOKENS + m0 + tid];
      wt_s[tid]  = wt [(size_t)list * NUM_TOKENS + m0 + tid];
    } else { tok_s[tid] = 0; wt_s[tid] = 0.f; }
  }
  __syncthreads();

  // staging: thread -> (row = tid/4, 8-elem chunk = tid%4); lds dest = tid*16B
  const int rr = tid >> 2;
  const int c8 = tid & 3;
  const bf16* gA0 = xbf + (size_t)tok_s[rr] * HIDDEN + c8 * 8;
  const bf16* gA1 = xbf + (size_t)tok_s[64 + rr] * HIDDEN + c8 * 8;
  const bf16* gB0 = wbf + (size_t)e * HIDDEN * HIDDEN
                  + (size_t)(nt * 128 + rr) * HIDDEN + c8 * 8;
  const bf16* gB1 = gB0 + (size_t)64 * HIDDEN;
  bf16* lA = As + tid * 8;
  bf16* lB = Bs + tid * 8;

  const int wid  = tid >> 6;
  const int lane = tid & 63;
  const int wm = (wid >> 1) * 64;
  const int wn = (wid & 1) * 64;
  const int qm = lane & 15;          // m (or n) within 16
  const int q8 = (lane >> 4) * 8;    // k chunk base within 32

  f32x4 acc[4][4];
#pragma unroll
  for (int i = 0; i < 4; ++i)
#pragma unroll
    for (int j = 0; j < 4; ++j) acc[i][j] = (f32x4){0.f, 0.f, 0.f, 0.f};

  for (int kc = 0; kc < HIDDEN; kc += 32) {
    gld_lds16(gA0 + kc, lA);
    gld_lds16(gA1 + kc, lA + 64 * 32);
    gld_lds16(gB0 + kc, lB);
    gld_lds16(gB1 + kc, lB + 64 * 32);
    __syncthreads();   // compiler emits s_waitcnt vmcnt(0) before barrier

    bf16x8 a[4], b[4];
#pragma unroll
    for (int i = 0; i < 4; ++i)
      a[i] = *(const bf16x8*)(As + (wm + i * 16 + qm) * 32 + q8);
#pragma unroll
    for (int j = 0; j < 4; ++j)
      b[j] = *(const bf16x8*)(Bs + (wn + j * 16 + qm) * 32 + q8);
#pragma unroll
    for (int i = 0; i < 4; ++i)
#pragma unroll
      for (int j = 0; j < 4; ++j)
        acc[i][j] = __builtin_amdgcn_mfma_f32_16x16x32_bf16(a[i], b[j], acc[i][j], 0, 0, 0);
    __syncthreads();   // before next chunk overwrites As/Bs
  }

  // epilogue: C/D layout col=lane&15, row=(lane>>4)*4+reg  (m89-verified)
  const int h0 = nt * 128 + wn + (lane & 15);
#pragma unroll
  for (int i = 0; i < 4; ++i) {
    const int rbase = wm + i * 16 + (lane >> 4) * 4;
#pragma unroll
    for (int r = 0; r < 4; ++r) {
      const int rl = rbase + r;
      if (rl < rows) {
        const int t = tok_s[rl];
        const float w = wt_s[rl];
        float* orow = out + (size_t)t * HIDDEN + h0;
#pragma unroll
        for (int j = 0; j < 4; ++j) {
          const float v = w * acc[i][j][r];
          if (PASS == 0) orow[j * 16] = v;
          else           orow[j * 16] += v;
        }
      }
    }
  }
}

// ---------------------------------------------------------------------------
extern "C" void kernel_launch(void* const* d_in, const int* in_sizes, int n_in,
                              void* d_out, int out_size, void* d_ws, size_t ws_size,
                              hipStream_t stream) {
  const float* x  = (const float*)d_in[0];
  const float* gw = (const float*)d_in[1];
  const float* ew = (const float*)d_in[2];
  float* out = (float*)d_out;

  // ws layout (~34.6 MB total)
  char* ws = (char*)d_ws;
  int*   cnt = (int*)ws;                                    // 16 ints
  int*   tok = (int*)(ws + 256);                            // 2*8*8192 ints = 512KB
  float* wt  = (float*)(ws + 256 + (size_t)16 * NUM_TOKENS * 4);       // 512KB
  bf16*  xbf = (bf16*)(ws + 256 + (size_t)32 * NUM_TOKENS * 4);        // 16MB
  bf16*  wbf = (bf16*)((char*)xbf + (size_t)NUM_TOKENS * HIDDEN * 2);  // 16MB

  hipMemsetAsync(cnt, 0, 16 * sizeof(int), stream);
  gate_route_kernel<<<NUM_TOKENS / 4, 256, 0, stream>>>(x, gw, xbf, cnt, tok, wt);
  convert_w_kernel<<<(NEXP * HIDDEN * HIDDEN) / (4 * 256), 256, 0, stream>>>(ew, wbf);

  dim3 grid(HIDDEN / 128, NUM_TOKENS / 128, NEXP);  // (8 n-tiles, 64 max m-tiles, 8 experts)
  moe_gemm_kernel<0><<<grid, 256, 0, stream>>>(xbf, wbf, cnt, tok, wt, out);
  moe_gemm_kernel<1><<<grid, 256, 0, stream>>>(xbf, wbf, cnt, tok, wt, out);
}

// Round 3
// 253.121 us; speedup vs baseline: 1.4739x; 1.4739x over previous
//
#include <hip/hip_runtime.h>
#include <hip/hip_bf16.h>
#include <stdint.h>

#define NUM_TOKENS 8192
#define HIDDEN 1024
#define NEXP 8
#define TOPK 2

typedef __bf16 bf16;
typedef __bf16 bf16x4 __attribute__((ext_vector_type(4)));
typedef __bf16 bf16x8 __attribute__((ext_vector_type(8)));
typedef float f32x4 __attribute__((ext_vector_type(4)));

// global -> LDS direct copy, 16B per lane. LDS dest must be lane-contiguous.
__device__ __forceinline__ void gld_lds16(const void* g, void* l) {
  __builtin_amdgcn_global_load_lds(
      (const __attribute__((address_space(1))) void*)(uintptr_t)g,
      (__attribute__((address_space(3))) void*)(uint32_t)(uintptr_t)l,
      16, 0, 0);
}

// ---------------------------------------------------------------------------
// Kernel 1: gating (fp32 exact) + per-token choice write + x fp32->bf16.
// One wave per token. No atomics (round-1 lesson: contended global atomics
// cost ~200us across 8 XCDs).
// ---------------------------------------------------------------------------
__global__ __launch_bounds__(256) void gate_route_kernel(
    const float* __restrict__ x, const float* __restrict__ gw,
    bf16* __restrict__ xbf, int* __restrict__ echoice, float* __restrict__ pchoice)
{
  const int wid  = threadIdx.x >> 6;
  const int lane = threadIdx.x & 63;
  const int t = blockIdx.x * 4 + wid;   // grid = 2048 -> t in [0, 8192)

  const float* xrow = x + (size_t)t * HIDDEN;
  bf16* xbrow = xbf + (size_t)t * HIDDEN;

  float acc[NEXP];
#pragma unroll
  for (int e = 0; e < NEXP; ++e) acc[e] = 0.f;

#pragma unroll
  for (int it = 0; it < 4; ++it) {
    const int idx = it * 256 + lane * 4;
    float4 xv = *(const float4*)(xrow + idx);
    bf16x4 xb;
    xb[0] = (bf16)xv.x; xb[1] = (bf16)xv.y; xb[2] = (bf16)xv.z; xb[3] = (bf16)xv.w;
    *(bf16x4*)(xbrow + idx) = xb;
#pragma unroll
    for (int e = 0; e < NEXP; ++e) {
      float4 gv = *(const float4*)(gw + e * HIDDEN + idx);
      acc[e] += xv.x * gv.x + xv.y * gv.y + xv.z * gv.z + xv.w * gv.w;
    }
  }
#pragma unroll
  for (int e = 0; e < NEXP; ++e) {
#pragma unroll
    for (int off = 32; off > 0; off >>= 1)
      acc[e] += __shfl_xor(acc[e], off, 64);
  }

  if (lane == 0) {
    float m = acc[0];
#pragma unroll
    for (int e = 1; e < NEXP; ++e) m = fmaxf(m, acc[e]);
    float p[NEXP]; float s = 0.f;
#pragma unroll
    for (int e = 0; e < NEXP; ++e) { p[e] = expf(acc[e] - m); s += p[e]; }
    const float inv = 1.f / s;
#pragma unroll
    for (int e = 0; e < NEXP; ++e) p[e] *= inv;
    // top-2, ties -> lower index (jax.lax.top_k semantics)
    int i0 = 0; float p0 = p[0];
#pragma unroll
    for (int e = 1; e < NEXP; ++e) if (p[e] > p0) { p0 = p[e]; i0 = e; }
    int i1 = -1; float p1 = -1.f;
#pragma unroll
    for (int e = 0; e < NEXP; ++e) if (e != i0 && p[e] > p1) { p1 = p[e]; i1 = e; }

    echoice[t]              = i0;
    echoice[NUM_TOKENS + t] = i1;
    pchoice[t]              = p0;
    pchoice[NUM_TOKENS + t] = p1;
  }
}

// ---------------------------------------------------------------------------
// Kernel 1b: DETERMINISTIC list compaction. 2 blocks (one wave each), one per
// top-k slot. No atomics, no LDS: rank within each 64-token chunk comes from
// ballot+popcount; running per-expert counters are wave-uniform. Lists come
// out sorted by token ID -> bit-identical every launch (round-2 lesson:
// LDS-atomic compaction diverged on graph replay).
// ---------------------------------------------------------------------------
__global__ __launch_bounds__(64) void build_lists_kernel(
    const int* __restrict__ echoice, const float* __restrict__ pchoice,
    int* __restrict__ cnt, int* __restrict__ tok, float* __restrict__ wt)
{
  const int k = blockIdx.x;       // slot 0 / 1
  const int lane = threadIdx.x;   // 0..63
  const int* ec = echoice + k * NUM_TOKENS;
  const float* pc = pchoice + k * NUM_TOKENS;

  int cl[NEXP];
#pragma unroll
  for (int e = 0; e < NEXP; ++e) cl[e] = 0;
  const unsigned long long lower = ((unsigned long long)1 << lane) - 1;

  for (int base = 0; base < NUM_TOKENS; base += 64) {
    const int t = base + lane;
    const int e = ec[t];
    const float p = pc[t];
    int pos = 0;
#pragma unroll
    for (int l = 0; l < NEXP; ++l) {
      const unsigned long long m = __ballot(e == l);
      if (e == l) pos = cl[l] + __popcll(m & lower);
      cl[l] += __popcll(m);
    }
    const int list = k * NEXP + e;
    tok[(size_t)list * NUM_TOKENS + pos] = t;
    wt [(size_t)list * NUM_TOKENS + pos] = p;
  }
  if (lane < NEXP) cnt[k * NEXP + lane] = cl[lane];
}

// ---------------------------------------------------------------------------
// Kernel 2: expert weights fp32 -> bf16
// ---------------------------------------------------------------------------
__global__ __launch_bounds__(256) void convert_w_kernel(
    const float* __restrict__ w, bf16* __restrict__ wbf)
{
  const size_t i = ((size_t)blockIdx.x * 256 + threadIdx.x) * 4;
  float4 v = *(const float4*)(w + i);
  bf16x4 b;
  b[0] = (bf16)v.x; b[1] = (bf16)v.y; b[2] = (bf16)v.z; b[3] = (bf16)v.w;
  *(bf16x4*)(wbf + i) = b;
}

// ---------------------------------------------------------------------------
// Kernel 3: grouped GEMM over one top-k slot. C[row,h] = sum_d X[tok[row],d]*W[e,h,d]
// 128x128 tile, BK=32, 4 waves of 4x4 mfma_f32_16x16x32_bf16 (m97 structure).
// PASS 0: out = w*y ; PASS 1: out += w*y  (separate launches -> no races)
// ---------------------------------------------------------------------------
template <int PASS>
__global__ __launch_bounds__(256) void moe_gemm_kernel(
    const bf16* __restrict__ xbf, const bf16* __restrict__ wbf,
    const int* __restrict__ cnt, const int* __restrict__ tok,
    const float* __restrict__ wt, float* __restrict__ out)
{
  const int e  = blockIdx.z;
  const int mt = blockIdx.y;
  const int nt = blockIdx.x;
  const int list = PASS * NEXP + e;
  const int count = cnt[list];
  const int m0 = mt * 128;
  if (m0 >= count) return;
  const int rows = min(128, count - m0);

  __shared__ __align__(16) bf16 As[128 * 32];
  __shared__ __align__(16) bf16 Bs[128 * 32];
  __shared__ int   tok_s[128];
  __shared__ float wt_s[128];

  const int tid = threadIdx.x;
  if (tid < 128) {
    if (tid < rows) {
      tok_s[tid] = tok[(size_t)list * NUM_TOKENS + m0 + tid];
      wt_s[tid]  = wt [(size_t)list * NUM_TOKENS + m0 + tid];
    } else { tok_s[tid] = 0; wt_s[tid] = 0.f; }
  }
  __syncthreads();

  // staging: thread -> (row = tid/4, 8-elem chunk = tid%4); lds dest = tid*16B
  const int rr = tid >> 2;
  const int c8 = tid & 3;
  const bf16* gA0 = xbf + (size_t)tok_s[rr] * HIDDEN + c8 * 8;
  const bf16* gA1 = xbf + (size_t)tok_s[64 + rr] * HIDDEN + c8 * 8;
  const bf16* gB0 = wbf + (size_t)e * HIDDEN * HIDDEN
                  + (size_t)(nt * 128 + rr) * HIDDEN + c8 * 8;
  const bf16* gB1 = gB0 + (size_t)64 * HIDDEN;
  bf16* lA = As + tid * 8;
  bf16* lB = Bs + tid * 8;

  const int wid  = tid >> 6;
  const int lane = tid & 63;
  const int wm = (wid >> 1) * 64;
  const int wn = (wid & 1) * 64;
  const int qm = lane & 15;          // m (or n) within 16
  const int q8 = (lane >> 4) * 8;    // k chunk base within 32

  f32x4 acc[4][4];
#pragma unroll
  for (int i = 0; i < 4; ++i)
#pragma unroll
    for (int j = 0; j < 4; ++j) acc[i][j] = (f32x4){0.f, 0.f, 0.f, 0.f};

  for (int kc = 0; kc < HIDDEN; kc += 32) {
    gld_lds16(gA0 + kc, lA);
    gld_lds16(gA1 + kc, lA + 64 * 32);
    gld_lds16(gB0 + kc, lB);
    gld_lds16(gB1 + kc, lB + 64 * 32);
    __syncthreads();

    bf16x8 a[4], b[4];
#pragma unroll
    for (int i = 0; i < 4; ++i)
      a[i] = *(const bf16x8*)(As + (wm + i * 16 + qm) * 32 + q8);
#pragma unroll
    for (int j = 0; j < 4; ++j)
      b[j] = *(const bf16x8*)(Bs + (wn + j * 16 + qm) * 32 + q8);
#pragma unroll
    for (int i = 0; i < 4; ++i)
#pragma unroll
      for (int j = 0; j < 4; ++j)
        acc[i][j] = __builtin_amdgcn_mfma_f32_16x16x32_bf16(a[i], b[j], acc[i][j], 0, 0, 0);
    __syncthreads();
  }

  // epilogue: C/D layout col=lane&15, row=(lane>>4)*4+reg  (m89-verified)
  const int h0 = nt * 128 + wn + (lane & 15);
#pragma unroll
  for (int i = 0; i < 4; ++i) {
    const int rbase = wm + i * 16 + (lane >> 4) * 4;
#pragma unroll
    for (int r = 0; r < 4; ++r) {
      const int rl = rbase + r;
      if (rl < rows) {
        const int t = tok_s[rl];
        const float w = wt_s[rl];
        float* orow = out + (size_t)t * HIDDEN + h0;
#pragma unroll
        for (int j = 0; j < 4; ++j) {
          const float v = w * acc[i][j][r];
          if (PASS == 0) orow[j * 16] = v;
          else           orow[j * 16] += v;
        }
      }
    }
  }
}

// ---------------------------------------------------------------------------
extern "C" void kernel_launch(void* const* d_in, const int* in_sizes, int n_in,
                              void* d_out, int out_size, void* d_ws, size_t ws_size,
                              hipStream_t stream) {
  const float* x  = (const float*)d_in[0];
  const float* gw = (const float*)d_in[1];
  const float* ew = (const float*)d_in[2];
  float* out = (float*)d_out;

  // ws layout
  char* ws = (char*)d_ws;
  int*   cnt     = (int*)ws;                                           // 16 ints
  int*   echoice = (int*)(ws + 256);                                   // 2*8192 ints
  float* pchoice = (float*)(ws + 256 + (size_t)2 * NUM_TOKENS * 4);    // 2*8192 f32
  int*   tok = (int*)(ws + 256 + (size_t)4 * NUM_TOKENS * 4);          // 16*8192 ints
  float* wt  = (float*)(ws + 256 + (size_t)20 * NUM_TOKENS * 4);       // 16*8192 f32
  bf16*  xbf = (bf16*)(ws + 256 + (size_t)36 * NUM_TOKENS * 4);        // 16MB
  bf16*  wbf = (bf16*)((char*)xbf + (size_t)NUM_TOKENS * HIDDEN * 2);  // 16MB

  gate_route_kernel<<<NUM_TOKENS / 4, 256, 0, stream>>>(x, gw, xbf, echoice, pchoice);
  build_lists_kernel<<<2, 64, 0, stream>>>(echoice, pchoice, cnt, tok, wt);
  convert_w_kernel<<<(NEXP * HIDDEN * HIDDEN) / (4 * 256), 256, 0, stream>>>(ew, wbf);

  dim3 grid(HIDDEN / 128, NUM_TOKENS / 128, NEXP);
  moe_gemm_kernel<0><<<grid, 256, 0, stream>>>(xbf, wbf, cnt, tok, wt, out);
  moe_gemm_kernel<1><<<grid, 256, 0, stream>>>(xbf, wbf, cnt, tok, wt, out);
}

// Round 4
// 213.111 us; speedup vs baseline: 1.7506x; 1.1877x over previous
//
#include <hip/hip_runtime.h>
#include <hip/hip_bf16.h>
#include <stdint.h>

#define NUM_TOKENS 8192
#define HIDDEN 1024
#define NEXP 8
#define TOPK 2

typedef __bf16 bf16;
typedef __bf16 bf16x4 __attribute__((ext_vector_type(4)));
typedef __bf16 bf16x8 __attribute__((ext_vector_type(8)));
typedef float f32x4 __attribute__((ext_vector_type(4)));

// global -> LDS direct copy, 16B per lane. LDS dest must be lane-contiguous.
__device__ __forceinline__ void gld_lds16(const void* g, void* l) {
  __builtin_amdgcn_global_load_lds(
      (const __attribute__((address_space(1))) void*)(uintptr_t)g,
      (__attribute__((address_space(3))) void*)(uint32_t)(uintptr_t)l,
      16, 0, 0);
}

// ---------------------------------------------------------------------------
// Kernel 1: gating (fp32 exact) + per-token choice write + x fp32->bf16.
// One wave per token. No atomics (round-1 lesson: contended global atomics
// cost ~200us across 8 XCDs).
// ---------------------------------------------------------------------------
__global__ __launch_bounds__(256) void gate_route_kernel(
    const float* __restrict__ x, const float* __restrict__ gw,
    bf16* __restrict__ xbf, int* __restrict__ echoice, float* __restrict__ pchoice)
{
  const int wid  = threadIdx.x >> 6;
  const int lane = threadIdx.x & 63;
  const int t = blockIdx.x * 4 + wid;   // grid = 2048 -> t in [0, 8192)

  const float* xrow = x + (size_t)t * HIDDEN;
  bf16* xbrow = xbf + (size_t)t * HIDDEN;

  float acc[NEXP];
#pragma unroll
  for (int e = 0; e < NEXP; ++e) acc[e] = 0.f;

#pragma unroll
  for (int it = 0; it < 4; ++it) {
    const int idx = it * 256 + lane * 4;
    float4 xv = *(const float4*)(xrow + idx);
    bf16x4 xb;
    xb[0] = (bf16)xv.x; xb[1] = (bf16)xv.y; xb[2] = (bf16)xv.z; xb[3] = (bf16)xv.w;
    *(bf16x4*)(xbrow + idx) = xb;
#pragma unroll
    for (int e = 0; e < NEXP; ++e) {
      float4 gv = *(const float4*)(gw + e * HIDDEN + idx);
      acc[e] += xv.x * gv.x + xv.y * gv.y + xv.z * gv.z + xv.w * gv.w;
    }
  }
#pragma unroll
  for (int e = 0; e < NEXP; ++e) {
#pragma unroll
    for (int off = 32; off > 0; off >>= 1)
      acc[e] += __shfl_xor(acc[e], off, 64);
  }

  if (lane == 0) {
    float m = acc[0];
#pragma unroll
    for (int e = 1; e < NEXP; ++e) m = fmaxf(m, acc[e]);
    float p[NEXP]; float s = 0.f;
#pragma unroll
    for (int e = 0; e < NEXP; ++e) { p[e] = expf(acc[e] - m); s += p[e]; }
    const float inv = 1.f / s;
#pragma unroll
    for (int e = 0; e < NEXP; ++e) p[e] *= inv;
    // top-2, ties -> lower index (jax.lax.top_k semantics)
    int i0 = 0; float p0 = p[0];
#pragma unroll
    for (int e = 1; e < NEXP; ++e) if (p[e] > p0) { p0 = p[e]; i0 = e; }
    int i1 = -1; float p1 = -1.f;
#pragma unroll
    for (int e = 0; e < NEXP; ++e) if (e != i0 && p[e] > p1) { p1 = p[e]; i1 = e; }

    echoice[t]              = i0;
    echoice[NUM_TOKENS + t] = i1;
    pchoice[t]              = p0;
    pchoice[NUM_TOKENS + t] = p1;
  }
}

// ---------------------------------------------------------------------------
// Kernel 1b: DETERMINISTIC two-phase list compaction. ONE block, 1024 threads
// = 16 waves; 8 waves per top-k slot, 1024 tokens per wave. Each lane
// preloads its 16 chunk values (independent loads -> overlapped; round-3
// lesson: the 2-wave version was a 128-step load-latency chain, 58.7us).
// Pass 1: ballot-count per (wave,expert) -> LDS; wave-offset prefix;
// Pass 2: ballot-rank scatter. No atomics; output order identical every
// launch (token-sorted), same as round-3's verified lists.
// ---------------------------------------------------------------------------
__global__ __launch_bounds__(1024) void build_lists_kernel(
    const int* __restrict__ echoice, const float* __restrict__ pchoice,
    int* __restrict__ cnt, int* __restrict__ tok, float* __restrict__ wt)
{
  const int tid  = threadIdx.x;
  const int wave = tid >> 6;      // 0..15
  const int lane = tid & 63;
  const int k = wave >> 3;        // top-k slot 0/1
  const int w = wave & 7;         // wave within slot
  const int tbase = w * 1024;     // this wave's token range

  const int*   ec = echoice + k * NUM_TOKENS;
  const float* pc = pchoice + k * NUM_TOKENS;

  __shared__ int wcnt[2][8][NEXP];
  __shared__ int woff[2][8][NEXP];

  const unsigned long long lower = ((unsigned long long)1 << lane) - 1;

  // preload: 16 chunks of 64 tokens, all independent
  int   ev[16];
  float pv[16];
#pragma unroll
  for (int c = 0; c < 16; ++c) {
    ev[c] = ec[tbase + c * 64 + lane];
    pv[c] = pc[tbase + c * 64 + lane];
  }

  // pass 1: per-wave per-expert counts
  int cl[NEXP];
#pragma unroll
  for (int e = 0; e < NEXP; ++e) cl[e] = 0;
#pragma unroll
  for (int c = 0; c < 16; ++c) {
#pragma unroll
    for (int l = 0; l < NEXP; ++l)
      cl[l] += __popcll(__ballot(ev[c] == l));
  }
  if (lane < NEXP) wcnt[k][w][lane] = cl[lane];
  __syncthreads();

  // exclusive prefix over waves (8 adds, done by 8 lanes per slot-wave)
  if (lane < NEXP) {
    int off = 0;
#pragma unroll
    for (int ww = 0; ww < 8; ++ww) {
      if (ww == w) woff[k][w][lane] = off;
      off += wcnt[k][ww][lane];
    }
    if (w == 0) cnt[k * NEXP + lane] = off;   // total over all 8 waves
  }
  __syncthreads();

  // pass 2: ballot-rank scatter from this wave's offsets
  int run[NEXP];
#pragma unroll
  for (int e = 0; e < NEXP; ++e) run[e] = woff[k][w][e];
#pragma unroll
  for (int c = 0; c < 16; ++c) {
    const int e = ev[c];
    int pos = 0;
#pragma unroll
    for (int l = 0; l < NEXP; ++l) {
      const unsigned long long m = __ballot(ev[c] == l);
      if (e == l) pos = run[l] + __popcll(m & lower);
      run[l] += __popcll(m);
    }
    const int list = k * NEXP + e;
    tok[(size_t)list * NUM_TOKENS + pos] = tbase + c * 64 + lane;
    wt [(size_t)list * NUM_TOKENS + pos] = pv[c];
  }
}

// ---------------------------------------------------------------------------
// Kernel 2: expert weights fp32 -> bf16
// ---------------------------------------------------------------------------
__global__ __launch_bounds__(256) void convert_w_kernel(
    const float* __restrict__ w, bf16* __restrict__ wbf)
{
  const size_t i = ((size_t)blockIdx.x * 256 + threadIdx.x) * 4;
  float4 v = *(const float4*)(w + i);
  bf16x4 b;
  b[0] = (bf16)v.x; b[1] = (bf16)v.y; b[2] = (bf16)v.z; b[3] = (bf16)v.w;
  *(bf16x4*)(wbf + i) = b;
}

// ---------------------------------------------------------------------------
// Kernel 3: grouped GEMM over one top-k slot. C[row,h] = sum_d X[tok[row],d]*W[e,h,d]
// 128x128 tile, BK=32, 4 waves of 4x4 mfma_f32_16x16x32_bf16 (m97 structure).
// PASS 0: out = w*y ; PASS 1: out += w*y  (separate launches -> no races)
// ---------------------------------------------------------------------------
template <int PASS>
__global__ __launch_bounds__(256) void moe_gemm_kernel(
    const bf16* __restrict__ xbf, const bf16* __restrict__ wbf,
    const int* __restrict__ cnt, const int* __restrict__ tok,
    const float* __restrict__ wt, float* __restrict__ out)
{
  const int e  = blockIdx.z;
  const int mt = blockIdx.y;
  const int nt = blockIdx.x;
  const int list = PASS * NEXP + e;
  const int count = cnt[list];
  const int m0 = mt * 128;
  if (m0 >= count) return;
  const int rows = min(128, count - m0);

  __shared__ __align__(16) bf16 As[128 * 32];
  __shared__ __align__(16) bf16 Bs[128 * 32];
  __shared__ int   tok_s[128];
  __shared__ float wt_s[128];

  const int tid = threadIdx.x;
  if (tid < 128) {
    if (tid < rows) {
      tok_s[tid] = tok[(size_t)list * NUM_TOKENS + m0 + tid];
      wt_s[tid]  = wt [(size_t)list * NUM_TOKENS + m0 + tid];
    } else { tok_s[tid] = 0; wt_s[tid] = 0.f; }
  }
  __syncthreads();

  // staging: thread -> (row = tid/4, 8-elem chunk = tid%4); lds dest = tid*16B
  const int rr = tid >> 2;
  const int c8 = tid & 3;
  const bf16* gA0 = xbf + (size_t)tok_s[rr] * HIDDEN + c8 * 8;
  const bf16* gA1 = xbf + (size_t)tok_s[64 + rr] * HIDDEN + c8 * 8;
  const bf16* gB0 = wbf + (size_t)e * HIDDEN * HIDDEN
                  + (size_t)(nt * 128 + rr) * HIDDEN + c8 * 8;
  const bf16* gB1 = gB0 + (size_t)64 * HIDDEN;
  bf16* lA = As + tid * 8;
  bf16* lB = Bs + tid * 8;

  const int wid  = tid >> 6;
  const int lane = tid & 63;
  const int wm = (wid >> 1) * 64;
  const int wn = (wid & 1) * 64;
  const int qm = lane & 15;          // m (or n) within 16
  const int q8 = (lane >> 4) * 8;    // k chunk base within 32

  f32x4 acc[4][4];
#pragma unroll
  for (int i = 0; i < 4; ++i)
#pragma unroll
    for (int j = 0; j < 4; ++j) acc[i][j] = (f32x4){0.f, 0.f, 0.f, 0.f};

  for (int kc = 0; kc < HIDDEN; kc += 32) {
    gld_lds16(gA0 + kc, lA);
    gld_lds16(gA1 + kc, lA + 64 * 32);
    gld_lds16(gB0 + kc, lB);
    gld_lds16(gB1 + kc, lB + 64 * 32);
    __syncthreads();

    bf16x8 a[4], b[4];
#pragma unroll
    for (int i = 0; i < 4; ++i)
      a[i] = *(const bf16x8*)(As + (wm + i * 16 + qm) * 32 + q8);
#pragma unroll
    for (int j = 0; j < 4; ++j)
      b[j] = *(const bf16x8*)(Bs + (wn + j * 16 + qm) * 32 + q8);
#pragma unroll
    for (int i = 0; i < 4; ++i)
#pragma unroll
      for (int j = 0; j < 4; ++j)
        acc[i][j] = __builtin_amdgcn_mfma_f32_16x16x32_bf16(a[i], b[j], acc[i][j], 0, 0, 0);
    __syncthreads();
  }

  // epilogue: C/D layout col=lane&15, row=(lane>>4)*4+reg  (m89-verified)
  const int h0 = nt * 128 + wn + (lane & 15);
#pragma unroll
  for (int i = 0; i < 4; ++i) {
    const int rbase = wm + i * 16 + (lane >> 4) * 4;
#pragma unroll
    for (int r = 0; r < 4; ++r) {
      const int rl = rbase + r;
      if (rl < rows) {
        const int t = tok_s[rl];
        const float w = wt_s[rl];
        float* orow = out + (size_t)t * HIDDEN + h0;
#pragma unroll
        for (int j = 0; j < 4; ++j) {
          const float v = w * acc[i][j][r];
          if (PASS == 0) orow[j * 16] = v;
          else           orow[j * 16] += v;
        }
      }
    }
  }
}

// ---------------------------------------------------------------------------
extern "C" void kernel_launch(void* const* d_in, const int* in_sizes, int n_in,
                              void* d_out, int out_size, void* d_ws, size_t ws_size,
                              hipStream_t stream) {
  const float* x  = (const float*)d_in[0];
  const float* gw = (const float*)d_in[1];
  const float* ew = (const float*)d_in[2];
  float* out = (float*)d_out;

  // ws layout
  char* ws = (char*)d_ws;
  int*   cnt     = (int*)ws;                                           // 16 ints
  int*   echoice = (int*)(ws + 256);                                   // 2*8192 ints
  float* pchoice = (float*)(ws + 256 + (size_t)2 * NUM_TOKENS * 4);    // 2*8192 f32
  int*   tok = (int*)(ws + 256 + (size_t)4 * NUM_TOKENS * 4);          // 16*8192 ints
  float* wt  = (float*)(ws + 256 + (size_t)20 * NUM_TOKENS * 4);       // 16*8192 f32
  bf16*  xbf = (bf16*)(ws + 256 + (size_t)36 * NUM_TOKENS * 4);        // 16MB
  bf16*  wbf = (bf16*)((char*)xbf + (size_t)NUM_TOKENS * HIDDEN * 2);  // 16MB

  gate_route_kernel<<<NUM_TOKENS / 4, 256, 0, stream>>>(x, gw, xbf, echoice, pchoice);
  build_lists_kernel<<<1, 1024, 0, stream>>>(echoice, pchoice, cnt, tok, wt);
  convert_w_kernel<<<(NEXP * HIDDEN * HIDDEN) / (4 * 256), 256, 0, stream>>>(ew, wbf);

  dim3 grid(HIDDEN / 128, NUM_TOKENS / 128, NEXP);
  moe_gemm_kernel<0><<<grid, 256, 0, stream>>>(xbf, wbf, cnt, tok, wt, out);
  moe_gemm_kernel<1><<<grid, 256, 0, stream>>>(xbf, wbf, cnt, tok, wt, out);
}